// Round 1
// baseline (4772.841 us; speedup 1.0000x reference)
//
#include <hip/hip_runtime.h>

#define NF 64

// ---------------- degree ----------------
__global__ void deg_kernel(const int* __restrict__ dst, float* __restrict__ deg, int n_edges) {
    int e = blockIdx.x * blockDim.x + threadIdx.x;
    if (e < n_edges) unsafeAtomicAdd(&deg[dst[e]], 1.0f);
}

__global__ void inv_kernel(float* __restrict__ deg, int n) {
    int i = blockIdx.x * blockDim.x + threadIdx.x;
    if (i < n) deg[i] = 1.0f / fmaxf(deg[i], 1.0f);
}

// ---------------- edge scatter: agg[dst] += h[src] ----------------
// 16 threads per edge, each handles a float4 chunk of the 64-wide row.
__global__ __launch_bounds__(256) void scatter_kernel(
    const float* __restrict__ h, const int* __restrict__ src, const int* __restrict__ dst,
    float* __restrict__ agg, int n_edges) {
    int t = blockIdx.x * blockDim.x + threadIdx.x;
    int e = t >> 4;
    if (e >= n_edges) return;
    int q = (t & 15) * 4;
    int s = src[e];
    int d = dst[e];
    float4 v = *reinterpret_cast<const float4*>(h + (size_t)s * NF + q);
    float* o = agg + (size_t)d * NF + q;
    unsafeAtomicAdd(o + 0, v.x);
    unsafeAtomicAdd(o + 1, v.y);
    unsafeAtomicAdd(o + 2, v.z);
    unsafeAtomicAdd(o + 3, v.w);
}

// ---------------- dense: out = [relu](h @ Ws + (agg*deginv) @ Wn + b) ----------------
// One wave per node; lane j computes output feature j. Weights staged in LDS.
__global__ __launch_bounds__(256) void linear_kernel(
    const float* __restrict__ h, const float* __restrict__ agg, const float* __restrict__ deginv,
    const float* __restrict__ Ws, const float* __restrict__ Wn, const float* __restrict__ bias,
    float* __restrict__ out, int n_nodes, int do_relu) {
    __shared__ float sWs[NF * NF];
    __shared__ float sWn[NF * NF];
    __shared__ float sb[NF];
    for (int i = threadIdx.x; i < NF * NF; i += 256) {
        sWs[i] = Ws[i];
        sWn[i] = Wn[i];
    }
    if (threadIdx.x < NF) sb[threadIdx.x] = bias[threadIdx.x];
    __syncthreads();

    int j = threadIdx.x & 63;
    int sub = threadIdx.x >> 6;  // wave id within block, 0..3

    for (int n = blockIdx.x * 4 + sub; n < n_nodes; n += gridDim.x * 4) {
        const float4* hr = reinterpret_cast<const float4*>(h + (size_t)n * NF);
        const float4* ar = reinterpret_cast<const float4*>(agg + (size_t)n * NF);
        float accS = 0.f, accN = 0.f;
#pragma unroll
        for (int k4 = 0; k4 < 16; ++k4) {
            float4 hv = hr[k4];  // wave-uniform address -> broadcast
            float4 av = ar[k4];
            int kb = k4 * 4;
            accS += hv.x * sWs[(kb + 0) * NF + j];
            accN += av.x * sWn[(kb + 0) * NF + j];
            accS += hv.y * sWs[(kb + 1) * NF + j];
            accN += av.y * sWn[(kb + 1) * NF + j];
            accS += hv.z * sWs[(kb + 2) * NF + j];
            accN += av.z * sWn[(kb + 2) * NF + j];
            accS += hv.w * sWs[(kb + 3) * NF + j];
            accN += av.w * sWn[(kb + 3) * NF + j];
        }
        float val = accS + deginv[n] * accN + sb[j];
        if (do_relu) val = fmaxf(val, 0.f);
        out[(size_t)n * NF + j] = val;
    }
}

extern "C" void kernel_launch(void* const* d_in, const int* in_sizes, int n_in,
                              void* d_out, int out_size, void* d_ws, size_t ws_size,
                              hipStream_t stream) {
    const float* features = (const float*)d_in[0];
    const int* src = (const int*)d_in[1];
    const int* dst = (const int*)d_in[2];
    const float* Ws0 = (const float*)d_in[3];
    const float* Wn0 = (const float*)d_in[4];
    const float* b0  = (const float*)d_in[5];
    const float* Ws1 = (const float*)d_in[6];
    const float* Wn1 = (const float*)d_in[7];
    const float* b1  = (const float*)d_in[8];
    const float* Ws2 = (const float*)d_in[9];
    const float* Wn2 = (const float*)d_in[10];
    const float* b2  = (const float*)d_in[11];

    const int n_nodes = in_sizes[0] / NF;
    const int n_edges = in_sizes[1];
    float* out = (float*)d_out;

    // workspace layout: deg[N] | agg[N*64] | h1[N*64]
    char* ws = (char*)d_ws;
    size_t degBytes = (((size_t)n_nodes * 4) + 255) / 256 * 256;
    float* deg = (float*)ws;
    float* agg = (float*)(ws + degBytes);
    float* h1  = agg + (size_t)n_nodes * NF;

    const size_t rowBytes = (size_t)n_nodes * NF * sizeof(float);

    dim3 blk(256);
    int degBlocks = (n_edges + 255) / 256;
    int invBlocks = (n_nodes + 255) / 256;
    int scatBlocks = (n_edges * 16 + 255) / 256;
    int linBlocks = (n_nodes + 3) / 4;

    // degrees -> deg_inv (in place)
    hipMemsetAsync(deg, 0, (size_t)n_nodes * sizeof(float), stream);
    deg_kernel<<<degBlocks, blk, 0, stream>>>(dst, deg, n_edges);
    inv_kernel<<<invBlocks, blk, 0, stream>>>(deg, n_nodes);

    // ---- layer 0: features -> d_out (relu) ----
    hipMemsetAsync(agg, 0, rowBytes, stream);
    scatter_kernel<<<scatBlocks, blk, 0, stream>>>(features, src, dst, agg, n_edges);
    linear_kernel<<<linBlocks, blk, 0, stream>>>(features, agg, deg, Ws0, Wn0, b0, out, n_nodes, 1);

    // ---- layer 1: d_out -> h1 (relu) ----
    hipMemsetAsync(agg, 0, rowBytes, stream);
    scatter_kernel<<<scatBlocks, blk, 0, stream>>>(out, src, dst, agg, n_edges);
    linear_kernel<<<linBlocks, blk, 0, stream>>>(out, agg, deg, Ws1, Wn1, b1, h1, n_nodes, 1);

    // ---- layer 2: h1 -> d_out (no relu) ----
    hipMemsetAsync(agg, 0, rowBytes, stream);
    scatter_kernel<<<scatBlocks, blk, 0, stream>>>(h1, src, dst, agg, n_edges);
    linear_kernel<<<linBlocks, blk, 0, stream>>>(h1, agg, deg, Ws2, Wn2, b2, out, n_nodes, 0);
}

// Round 2
// 1243.169 us; speedup vs baseline: 3.8393x; 3.8393x over previous
//
#include <hip/hip_runtime.h>

#define NF 64

// ======================= CSR build =======================

__global__ void hist_kernel(const int* __restrict__ dst, int* __restrict__ cnt, int n_edges) {
    int e = blockIdx.x * blockDim.x + threadIdx.x;
    if (e < n_edges) atomicAdd(&cnt[dst[e]], 1);
}

// per-block partial sums (1024 elements per block)
__global__ void scan1_kernel(const int* __restrict__ cnt, int* __restrict__ bsum, int n) {
    __shared__ int sd[256];
    int base = blockIdx.x * 1024 + threadIdx.x * 4;
    int s = 0;
#pragma unroll
    for (int i = 0; i < 4; ++i) { int idx = base + i; if (idx < n) s += cnt[idx]; }
    sd[threadIdx.x] = s;
    __syncthreads();
    for (int off = 128; off > 0; off >>= 1) {
        if (threadIdx.x < off) sd[threadIdx.x] += sd[threadIdx.x + off];
        __syncthreads();
    }
    if (threadIdx.x == 0) bsum[blockIdx.x] = sd[0];
}

// exclusive scan of block sums (single block; nb <= 1024)
__global__ void scan2_kernel(int* __restrict__ bsum, int nb) {
    __shared__ int sd[1024];
    for (int i = threadIdx.x; i < nb; i += blockDim.x) sd[i] = bsum[i];
    __syncthreads();
    if (threadIdx.x == 0) {
        int run = 0;
        for (int i = 0; i < nb; ++i) { int v = sd[i]; sd[i] = run; run += v; }
    }
    __syncthreads();
    for (int i = threadIdx.x; i < nb; i += blockDim.x) bsum[i] = sd[i];
}

// block-local exclusive scan + block offset -> row_ptr; also deg_inv
__global__ void scan3_kernel(const int* __restrict__ cnt, const int* __restrict__ bsum,
                             int* __restrict__ row_ptr, float* __restrict__ deginv,
                             int n, int n_edges) {
    __shared__ int a[256], b[256];
    int tid = threadIdx.x;
    int base = blockIdx.x * 1024 + tid * 4;
    int v[4]; int s = 0;
#pragma unroll
    for (int i = 0; i < 4; ++i) { int idx = base + i; v[i] = (idx < n) ? cnt[idx] : 0; s += v[i]; }
    a[tid] = s;
    __syncthreads();
    int* pin = a; int* pout = b;
    for (int off = 1; off < 256; off <<= 1) {
        pout[tid] = (tid >= off) ? (pin[tid - off] + pin[tid]) : pin[tid];
        __syncthreads();
        int* t = pin; pin = pout; pout = t;
    }
    int run = bsum[blockIdx.x] + ((tid > 0) ? pin[tid - 1] : 0);
#pragma unroll
    for (int i = 0; i < 4; ++i) {
        int idx = base + i;
        if (idx < n) {
            row_ptr[idx] = run;
            deginv[idx] = 1.0f / fmaxf((float)v[i], 1.0f);
            run += v[i];
        }
    }
    if (blockIdx.x == 0 && tid == 0) row_ptr[n] = n_edges;
}

__global__ void fill_kernel(const int* __restrict__ src, const int* __restrict__ dst,
                            const int* __restrict__ row_ptr, int* __restrict__ cur,
                            int* __restrict__ col, int n_edges) {
    int e = blockIdx.x * blockDim.x + threadIdx.x;
    if (e < n_edges) {
        int d = dst[e];
        int pos = row_ptr[d] + atomicAdd(&cur[d], 1);
        col[pos] = src[e];
    }
}

// ======================= aggregation (CSR gather) =======================
// one wave per node; lane j owns feature j; applies deg_inv.
__global__ __launch_bounds__(256) void aggregate_kernel(
    const float* __restrict__ h, const int* __restrict__ row_ptr, const int* __restrict__ col,
    const float* __restrict__ deginv, float* __restrict__ agg, int n_nodes) {
    int lane = threadIdx.x & 63;
    int wid = threadIdx.x >> 6;
    int n = blockIdx.x * 4 + wid;
    if (n >= n_nodes) return;
    int beg = row_ptr[n], end = row_ptr[n + 1];
    float acc = 0.f;
    int i = beg;
    for (; i + 1 < end; i += 2) {
        int s0 = col[i];
        int s1 = col[i + 1];
        float v0 = h[(size_t)s0 * NF + lane];
        float v1 = h[(size_t)s1 * NF + lane];
        acc += v0 + v1;
    }
    if (i < end) acc += h[(size_t)col[i] * NF + lane];
    agg[(size_t)n * NF + lane] = acc * deginv[n];
}

// ======================= dense: out = [relu](h @ Ws + agg @ Wn + b) ====
// agg already mean-scaled (apply_deginv=0) in CSR path; scatter fallback
// passes apply_deginv=1 with raw sums.
__global__ __launch_bounds__(256) void linear_kernel(
    const float* __restrict__ h, const float* __restrict__ agg, const float* __restrict__ deginv,
    const float* __restrict__ Ws, const float* __restrict__ Wn, const float* __restrict__ bias,
    float* __restrict__ out, int n_nodes, int do_relu, int apply_deginv) {
    __shared__ float sWs[NF * NF];
    __shared__ float sWn[NF * NF];
    __shared__ float sb[NF];
    for (int i = threadIdx.x; i < NF * NF; i += 256) {
        sWs[i] = Ws[i];
        sWn[i] = Wn[i];
    }
    if (threadIdx.x < NF) sb[threadIdx.x] = bias[threadIdx.x];
    __syncthreads();

    int j = threadIdx.x & 63;
    int sub = threadIdx.x >> 6;

    for (int n = blockIdx.x * 4 + sub; n < n_nodes; n += gridDim.x * 4) {
        const float4* hr = reinterpret_cast<const float4*>(h + (size_t)n * NF);
        const float4* ar = reinterpret_cast<const float4*>(agg + (size_t)n * NF);
        float accS = 0.f, accN = 0.f;
#pragma unroll
        for (int k4 = 0; k4 < 16; ++k4) {
            float4 hv = hr[k4];
            float4 av = ar[k4];
            int kb = k4 * 4;
            accS += hv.x * sWs[(kb + 0) * NF + j];
            accN += av.x * sWn[(kb + 0) * NF + j];
            accS += hv.y * sWs[(kb + 1) * NF + j];
            accN += av.y * sWn[(kb + 1) * NF + j];
            accS += hv.z * sWs[(kb + 2) * NF + j];
            accN += av.z * sWn[(kb + 2) * NF + j];
            accS += hv.w * sWs[(kb + 3) * NF + j];
            accN += av.w * sWn[(kb + 3) * NF + j];
        }
        float nmul = apply_deginv ? deginv[n] : 1.0f;
        float val = accS + nmul * accN + sb[j];
        if (do_relu) val = fmaxf(val, 0.f);
        out[(size_t)n * NF + j] = val;
    }
}

// ======================= round-1 fallback scatter ======================
__global__ void deg_kernel(const int* __restrict__ dst, float* __restrict__ deg, int n_edges) {
    int e = blockIdx.x * blockDim.x + threadIdx.x;
    if (e < n_edges) unsafeAtomicAdd(&deg[dst[e]], 1.0f);
}

__global__ void inv_kernel(float* __restrict__ deg, int n) {
    int i = blockIdx.x * blockDim.x + threadIdx.x;
    if (i < n) deg[i] = 1.0f / fmaxf(deg[i], 1.0f);
}

__global__ __launch_bounds__(256) void scatter_kernel(
    const float* __restrict__ h, const int* __restrict__ src, const int* __restrict__ dst,
    float* __restrict__ agg, int n_edges) {
    int t = blockIdx.x * blockDim.x + threadIdx.x;
    int e = t >> 4;
    if (e >= n_edges) return;
    int q = (t & 15) * 4;
    int s = src[e];
    int d = dst[e];
    float4 v = *reinterpret_cast<const float4*>(h + (size_t)s * NF + q);
    float* o = agg + (size_t)d * NF + q;
    unsafeAtomicAdd(o + 0, v.x);
    unsafeAtomicAdd(o + 1, v.y);
    unsafeAtomicAdd(o + 2, v.z);
    unsafeAtomicAdd(o + 3, v.w);
}

// ======================= launch =======================

extern "C" void kernel_launch(void* const* d_in, const int* in_sizes, int n_in,
                              void* d_out, int out_size, void* d_ws, size_t ws_size,
                              hipStream_t stream) {
    const float* features = (const float*)d_in[0];
    const int* src = (const int*)d_in[1];
    const int* dst = (const int*)d_in[2];
    const float* Ws0 = (const float*)d_in[3];
    const float* Wn0 = (const float*)d_in[4];
    const float* b0  = (const float*)d_in[5];
    const float* Ws1 = (const float*)d_in[6];
    const float* Wn1 = (const float*)d_in[7];
    const float* b1  = (const float*)d_in[8];
    const float* Ws2 = (const float*)d_in[9];
    const float* Wn2 = (const float*)d_in[10];
    const float* b2  = (const float*)d_in[11];

    const int n_nodes = in_sizes[0] / NF;
    const int n_edges = in_sizes[1];
    float* out = (float*)d_out;

    const size_t rowBytes = (size_t)n_nodes * NF * sizeof(float);
    const size_t alignN = (((size_t)n_nodes + 64) * 4 + 255) / 256 * 256;  // N+1 ints, padded
    const size_t alignE = ((size_t)n_edges * 4 + 255) / 256 * 256;

    dim3 blk(256);
    const int eBlocks = (n_edges + 255) / 256;
    const int nBlocks1024 = (n_nodes + 1023) / 1024;
    const int waveBlocks = (n_nodes + 3) / 4;

    // CSR-path workspace: cnt | row_ptr | deginv | col | agg | h1
    const size_t csrNeed = alignN * 3 + alignE + 2 * rowBytes;

    if (ws_size >= csrNeed) {
        char* ws = (char*)d_ws;
        int* cnt     = (int*)ws;
        int* row_ptr = (int*)(ws + alignN);
        float* deginv = (float*)(ws + 2 * alignN);
        int* col     = (int*)(ws + 3 * alignN);
        float* agg   = (float*)(ws + 3 * alignN + alignE);
        float* h1    = agg + (size_t)n_nodes * NF;
        // bsum: borrow the tail of h1's 25.6MB? No — use cnt after it's consumed.
        // We need bsum live across scan1..scan3 while cnt is still needed; put
        // bsum in the padding-safe spot: reuse deginv's storage BEFORE deginv
        // is written (scan3 writes deginv after reading bsum -> conflict-free
        // only if bsum != deginv region). Use a small dedicated slice at the
        // very end of ws instead.
        int* bsum = (int*)(ws + ws_size - 8192);

        // 1) histogram of dst
        hipMemsetAsync(cnt, 0, (size_t)n_nodes * sizeof(int), stream);
        hist_kernel<<<eBlocks, blk, 0, stream>>>(dst, cnt, n_edges);
        // 2) scan -> row_ptr, deginv
        scan1_kernel<<<nBlocks1024, blk, 0, stream>>>(cnt, bsum, n_nodes);
        scan2_kernel<<<1, 1024, 0, stream>>>(bsum, nBlocks1024);
        scan3_kernel<<<nBlocks1024, blk, 0, stream>>>(cnt, bsum, row_ptr, deginv, n_nodes, n_edges);
        // 3) fill col (reuse cnt as running cursor)
        hipMemsetAsync(cnt, 0, (size_t)n_nodes * sizeof(int), stream);
        fill_kernel<<<eBlocks, blk, 0, stream>>>(src, dst, row_ptr, cnt, col, n_edges);

        // layer 0
        aggregate_kernel<<<waveBlocks, blk, 0, stream>>>(features, row_ptr, col, deginv, agg, n_nodes);
        linear_kernel<<<waveBlocks, blk, 0, stream>>>(features, agg, deginv, Ws0, Wn0, b0, out, n_nodes, 1, 0);
        // layer 1
        aggregate_kernel<<<waveBlocks, blk, 0, stream>>>(out, row_ptr, col, deginv, agg, n_nodes);
        linear_kernel<<<waveBlocks, blk, 0, stream>>>(out, agg, deginv, Ws1, Wn1, b1, h1, n_nodes, 1, 0);
        // layer 2
        aggregate_kernel<<<waveBlocks, blk, 0, stream>>>(h1, row_ptr, col, deginv, agg, n_nodes);
        linear_kernel<<<waveBlocks, blk, 0, stream>>>(h1, agg, deginv, Ws2, Wn2, b2, out, n_nodes, 0, 0);
    } else {
        // fallback: round-1 atomic-scatter path
        char* ws = (char*)d_ws;
        size_t degBytes = (((size_t)n_nodes * 4) + 255) / 256 * 256;
        float* deg = (float*)ws;
        float* agg = (float*)(ws + degBytes);
        float* h1  = agg + (size_t)n_nodes * NF;
        int scatBlocks = (n_edges * 16 + 255) / 256;

        hipMemsetAsync(deg, 0, (size_t)n_nodes * sizeof(float), stream);
        deg_kernel<<<eBlocks, blk, 0, stream>>>(dst, deg, n_edges);
        inv_kernel<<<(n_nodes + 255) / 256, blk, 0, stream>>>(deg, n_nodes);

        hipMemsetAsync(agg, 0, rowBytes, stream);
        scatter_kernel<<<scatBlocks, blk, 0, stream>>>(features, src, dst, agg, n_edges);
        linear_kernel<<<waveBlocks, blk, 0, stream>>>(features, agg, deg, Ws0, Wn0, b0, out, n_nodes, 1, 1);

        hipMemsetAsync(agg, 0, rowBytes, stream);
        scatter_kernel<<<scatBlocks, blk, 0, stream>>>(out, src, dst, agg, n_edges);
        linear_kernel<<<waveBlocks, blk, 0, stream>>>(out, agg, deg, Ws1, Wn1, b1, h1, n_nodes, 1, 1);

        hipMemsetAsync(agg, 0, rowBytes, stream);
        scatter_kernel<<<scatBlocks, blk, 0, stream>>>(h1, src, dst, agg, n_edges);
        linear_kernel<<<waveBlocks, blk, 0, stream>>>(h1, agg, deg, Ws2, Wn2, b2, out, n_nodes, 0, 1);
    }
}

// Round 3
// 445.803 us; speedup vs baseline: 10.7062x; 2.7886x over previous
//
#include <hip/hip_runtime.h>

#define NF 64

typedef __attribute__((ext_vector_type(8))) short bf16x8;
typedef __attribute__((ext_vector_type(4))) float f32x4;

__device__ __forceinline__ float bf2f(unsigned short x) {
    union { unsigned int u; float f; } v; v.u = ((unsigned int)x) << 16; return v.f;
}
__device__ __forceinline__ unsigned short f2bf(float x) {
    union { float f; unsigned int u; } v; v.f = x;
    unsigned int r = (v.u + 0x7FFFu + ((v.u >> 16) & 1u)) >> 16;
    return (unsigned short)r;
}

// ======================= CSR build =======================

__global__ void hist_kernel(const int* __restrict__ dst, int* __restrict__ cnt, int n_edges) {
    int e = blockIdx.x * blockDim.x + threadIdx.x;
    if (e < n_edges) atomicAdd(&cnt[dst[e]], 1);
}

__global__ void scan1_kernel(const int* __restrict__ cnt, int* __restrict__ bsum, int n) {
    __shared__ int sd[256];
    int base = blockIdx.x * 1024 + threadIdx.x * 4;
    int s = 0;
#pragma unroll
    for (int i = 0; i < 4; ++i) { int idx = base + i; if (idx < n) s += cnt[idx]; }
    sd[threadIdx.x] = s;
    __syncthreads();
    for (int off = 128; off > 0; off >>= 1) {
        if (threadIdx.x < off) sd[threadIdx.x] += sd[threadIdx.x + off];
        __syncthreads();
    }
    if (threadIdx.x == 0) bsum[blockIdx.x] = sd[0];
}

__global__ void scan2_kernel(int* __restrict__ bsum, int nb) {
    __shared__ int sd[1024];
    for (int i = threadIdx.x; i < nb; i += blockDim.x) sd[i] = bsum[i];
    __syncthreads();
    if (threadIdx.x == 0) {
        int run = 0;
        for (int i = 0; i < nb; ++i) { int v = sd[i]; sd[i] = run; run += v; }
    }
    __syncthreads();
    for (int i = threadIdx.x; i < nb; i += blockDim.x) bsum[i] = sd[i];
}

__global__ void scan3_kernel(const int* __restrict__ cnt, const int* __restrict__ bsum,
                             int* __restrict__ row_ptr, float* __restrict__ deginv,
                             int n, int n_edges) {
    __shared__ int a[256], b[256];
    int tid = threadIdx.x;
    int base = blockIdx.x * 1024 + tid * 4;
    int v[4]; int s = 0;
#pragma unroll
    for (int i = 0; i < 4; ++i) { int idx = base + i; v[i] = (idx < n) ? cnt[idx] : 0; s += v[i]; }
    a[tid] = s;
    __syncthreads();
    int* pin = a; int* pout = b;
    for (int off = 1; off < 256; off <<= 1) {
        pout[tid] = (tid >= off) ? (pin[tid - off] + pin[tid]) : pin[tid];
        __syncthreads();
        int* t = pin; pin = pout; pout = t;
    }
    int run = bsum[blockIdx.x] + ((tid > 0) ? pin[tid - 1] : 0);
#pragma unroll
    for (int i = 0; i < 4; ++i) {
        int idx = base + i;
        if (idx < n) {
            row_ptr[idx] = run;
            deginv[idx] = 1.0f / fmaxf((float)v[i], 1.0f);
            run += v[i];
        }
    }
    if (blockIdx.x == 0 && tid == 0) row_ptr[n] = n_edges;
}

__global__ void fill_kernel(const int* __restrict__ src, const int* __restrict__ dst,
                            const int* __restrict__ row_ptr, int* __restrict__ cur,
                            int* __restrict__ col, int n_edges) {
    int e = blockIdx.x * blockDim.x + threadIdx.x;
    if (e < n_edges) {
        int d = dst[e];
        int pos = row_ptr[d] + atomicAdd(&cur[d], 1);
        col[pos] = src[e];
    }
}

// ================= bf16 staging =================

// features f32 [N][64] -> X[:, 0:64] bf16 (row stride 128)
__global__ void convert_kernel(const float* __restrict__ in, unsigned short* __restrict__ X, int n_nodes) {
    int t = blockIdx.x * blockDim.x + threadIdx.x;
    int total = n_nodes * 16;
    if (t >= total) return;
    int n = t >> 4, g = t & 15;
    float4 v = *reinterpret_cast<const float4*>(in + (size_t)n * 64 + g * 4);
    ushort4 o;
    o.x = f2bf(v.x); o.y = f2bf(v.y); o.z = f2bf(v.z); o.w = f2bf(v.w);
    *reinterpret_cast<ushort4*>(X + (size_t)n * 128 + g * 4) = o;
}

// WT[j][k] = (k<64 ? Ws[k][j] : Wn[k-64][j]) as bf16; WT is [64][128]
__global__ void wtrans_kernel(const float* __restrict__ Ws, const float* __restrict__ Wn,
                              unsigned short* __restrict__ WT) {
    int t = blockIdx.x * blockDim.x + threadIdx.x;
    if (t >= 64 * 128) return;
    int j = t >> 7, k = t & 127;
    float v = (k < 64) ? Ws[k * 64 + j] : Wn[(k - 64) * 64 + j];
    WT[(size_t)j * 128 + k] = f2bf(v);
}

// ================= aggregation (CSR gather, bf16) =================
// one wave per node; lane j owns feature j; reads h-half (cols 0..63) of X,
// writes mean into agg-half (cols 64..127). Disjoint column ranges -> no race.
__global__ __launch_bounds__(256) void aggregate_bf16_kernel(
    unsigned short* __restrict__ X, const int* __restrict__ row_ptr, const int* __restrict__ col,
    const float* __restrict__ deginv, int n_nodes) {
    int lane = threadIdx.x & 63;
    int wid = threadIdx.x >> 6;
    int n = blockIdx.x * 4 + wid;
    if (n >= n_nodes) return;
    int beg = row_ptr[n], end = row_ptr[n + 1];
    float acc = 0.f;
    int i = beg;
    for (; i + 3 < end; i += 4) {
        int s0 = col[i], s1 = col[i + 1], s2 = col[i + 2], s3 = col[i + 3];
        float v0 = bf2f(X[(size_t)s0 * 128 + lane]);
        float v1 = bf2f(X[(size_t)s1 * 128 + lane]);
        float v2 = bf2f(X[(size_t)s2 * 128 + lane]);
        float v3 = bf2f(X[(size_t)s3 * 128 + lane]);
        acc += (v0 + v1) + (v2 + v3);
    }
    for (; i < end; ++i) acc += bf2f(X[(size_t)col[i] * 128 + lane]);
    X[(size_t)n * 128 + 64 + lane] = f2bf(acc * deginv[n]);
}

// ================= MFMA linear =================
// OUT[node][feat] = [relu]( X[node][0:128] @ WT^T + b )
// C-tile: M=feat(16), N=node(16). A = WT rows (feat-major, k contiguous),
// B = X rows (node-major, k contiguous). Frag: lane l elem e = M[l&15][(l>>4)*8+e]
// (combination ref-verified in learn_hip m97). C: col=lane&15(node), row=(lane>>4)*4+r(feat).
__global__ __launch_bounds__(256) void linear_mfma_kernel(
    const unsigned short* __restrict__ X, const unsigned short* __restrict__ WT,
    const float* __restrict__ bias, unsigned short* __restrict__ outBf,
    float* __restrict__ outF32, int n_nodes, int do_relu) {
    int lane = threadIdx.x & 63;
    int wid = threadIdx.x >> 6;
    int l15 = lane & 15;
    int lg = lane >> 4;

    // weights in registers: 16 frags x 4 VGPR = 64 VGPR
    bf16x8 wf[4][4];
#pragma unroll
    for (int ft = 0; ft < 4; ++ft)
#pragma unroll
        for (int ks = 0; ks < 4; ++ks)
            wf[ft][ks] = *reinterpret_cast<const bf16x8*>(
                WT + (size_t)(ft * 16 + l15) * 128 + ks * 32 + lg * 8);

    float4 bv[4];
#pragma unroll
    for (int ft = 0; ft < 4; ++ft)
        bv[ft] = *reinterpret_cast<const float4*>(bias + ft * 16 + lg * 4);

    int tiles = (n_nodes + 15) >> 4;
    for (int tile = blockIdx.x * 4 + wid; tile < tiles; tile += gridDim.x * 4) {
        int nodeBase = tile * 16;
        int nrow = nodeBase + l15;
        int rrow = nrow < n_nodes ? nrow : n_nodes - 1;  // clamp loads; stores masked below

        bf16x8 xf[4];
#pragma unroll
        for (int ks = 0; ks < 4; ++ks)
            xf[ks] = *reinterpret_cast<const bf16x8*>(X + (size_t)rrow * 128 + ks * 32 + lg * 8);

        f32x4 acc[4];
#pragma unroll
        for (int ft = 0; ft < 4; ++ft) acc[ft] = (f32x4){0.f, 0.f, 0.f, 0.f};
#pragma unroll
        for (int ks = 0; ks < 4; ++ks) {
#pragma unroll
            for (int ft = 0; ft < 4; ++ft)
                acc[ft] = __builtin_amdgcn_mfma_f32_16x16x32_bf16(wf[ft][ks], xf[ks], acc[ft], 0, 0, 0);
        }

        if (nrow < n_nodes) {
#pragma unroll
            for (int ft = 0; ft < 4; ++ft) {
                float4 v;
                v.x = acc[ft][0] + bv[ft].x;
                v.y = acc[ft][1] + bv[ft].y;
                v.z = acc[ft][2] + bv[ft].z;
                v.w = acc[ft][3] + bv[ft].w;
                if (do_relu) {
                    v.x = fmaxf(v.x, 0.f); v.y = fmaxf(v.y, 0.f);
                    v.z = fmaxf(v.z, 0.f); v.w = fmaxf(v.w, 0.f);
                }
                int fbase = ft * 16 + lg * 4;
                if (outF32) {
                    *reinterpret_cast<float4*>(outF32 + (size_t)nrow * 64 + fbase) = v;
                } else {
                    ushort4 o;
                    o.x = f2bf(v.x); o.y = f2bf(v.y); o.z = f2bf(v.z); o.w = f2bf(v.w);
                    *reinterpret_cast<ushort4*>(outBf + (size_t)nrow * 128 + fbase) = o;
                }
            }
        }
    }
}

// ======================= round-1 fallback (atomic scatter, f32) ==========

__global__ void deg_kernel(const int* __restrict__ dst, float* __restrict__ deg, int n_edges) {
    int e = blockIdx.x * blockDim.x + threadIdx.x;
    if (e < n_edges) unsafeAtomicAdd(&deg[dst[e]], 1.0f);
}

__global__ void inv_kernel(float* __restrict__ deg, int n) {
    int i = blockIdx.x * blockDim.x + threadIdx.x;
    if (i < n) deg[i] = 1.0f / fmaxf(deg[i], 1.0f);
}

__global__ __launch_bounds__(256) void scatter_kernel(
    const float* __restrict__ h, const int* __restrict__ src, const int* __restrict__ dst,
    float* __restrict__ agg, int n_edges) {
    int t = blockIdx.x * blockDim.x + threadIdx.x;
    int e = t >> 4;
    if (e >= n_edges) return;
    int q = (t & 15) * 4;
    int s = src[e];
    int d = dst[e];
    float4 v = *reinterpret_cast<const float4*>(h + (size_t)s * NF + q);
    float* o = agg + (size_t)d * NF + q;
    unsafeAtomicAdd(o + 0, v.x);
    unsafeAtomicAdd(o + 1, v.y);
    unsafeAtomicAdd(o + 2, v.z);
    unsafeAtomicAdd(o + 3, v.w);
}

__global__ __launch_bounds__(256) void linear_kernel(
    const float* __restrict__ h, const float* __restrict__ agg, const float* __restrict__ deginv,
    const float* __restrict__ Ws, const float* __restrict__ Wn, const float* __restrict__ bias,
    float* __restrict__ out, int n_nodes, int do_relu, int apply_deginv) {
    __shared__ float sWs[NF * NF];
    __shared__ float sWn[NF * NF];
    __shared__ float sb[NF];
    for (int i = threadIdx.x; i < NF * NF; i += 256) {
        sWs[i] = Ws[i];
        sWn[i] = Wn[i];
    }
    if (threadIdx.x < NF) sb[threadIdx.x] = bias[threadIdx.x];
    __syncthreads();
    int j = threadIdx.x & 63;
    int sub = threadIdx.x >> 6;
    for (int n = blockIdx.x * 4 + sub; n < n_nodes; n += gridDim.x * 4) {
        const float4* hr = reinterpret_cast<const float4*>(h + (size_t)n * NF);
        const float4* ar = reinterpret_cast<const float4*>(agg + (size_t)n * NF);
        float accS = 0.f, accN = 0.f;
#pragma unroll
        for (int k4 = 0; k4 < 16; ++k4) {
            float4 hv = hr[k4];
            float4 av = ar[k4];
            int kb = k4 * 4;
            accS += hv.x * sWs[(kb + 0) * NF + j];
            accN += av.x * sWn[(kb + 0) * NF + j];
            accS += hv.y * sWs[(kb + 1) * NF + j];
            accN += av.y * sWn[(kb + 1) * NF + j];
            accS += hv.z * sWs[(kb + 2) * NF + j];
            accN += av.z * sWn[(kb + 2) * NF + j];
            accS += hv.w * sWs[(kb + 3) * NF + j];
            accN += av.w * sWn[(kb + 3) * NF + j];
        }
        float nmul = apply_deginv ? deginv[n] : 1.0f;
        float val = accS + nmul * accN + sb[j];
        if (do_relu) val = fmaxf(val, 0.f);
        out[(size_t)n * NF + j] = val;
    }
}

// ======================= launch =======================

extern "C" void kernel_launch(void* const* d_in, const int* in_sizes, int n_in,
                              void* d_out, int out_size, void* d_ws, size_t ws_size,
                              hipStream_t stream) {
    const float* features = (const float*)d_in[0];
    const int* src = (const int*)d_in[1];
    const int* dst = (const int*)d_in[2];
    const float* Ws0 = (const float*)d_in[3];
    const float* Wn0 = (const float*)d_in[4];
    const float* b0  = (const float*)d_in[5];
    const float* Ws1 = (const float*)d_in[6];
    const float* Wn1 = (const float*)d_in[7];
    const float* b1  = (const float*)d_in[8];
    const float* Ws2 = (const float*)d_in[9];
    const float* Wn2 = (const float*)d_in[10];
    const float* b2  = (const float*)d_in[11];

    const int n_nodes = in_sizes[0] / NF;
    const int n_edges = in_sizes[1];
    float* out = (float*)d_out;

    const size_t alignN = (((size_t)n_nodes + 64) * 4 + 255) / 256 * 256;
    const size_t alignE = ((size_t)n_edges * 4 + 255) / 256 * 256;
    const size_t xBytes = ((size_t)n_nodes * 128 * 2 + 255) / 256 * 256;
    const size_t wtBytes = 64 * 128 * 2;

    dim3 blk(256);
    const int eBlocks = (n_edges + 255) / 256;
    const int nBlocks1024 = (n_nodes + 1023) / 1024;
    const int waveBlocks = (n_nodes + 3) / 4;
    const int tiles = (n_nodes + 15) / 16;
    const int linBlocks = ((tiles + 3) / 4 < 640) ? (tiles + 3) / 4 : 640;

    // layout: cnt | row_ptr | deginv | col | X0 | X1 | WT0 WT1 WT2 | bsum
    const size_t csrNeed = 3 * alignN + alignE + 2 * xBytes + 3 * wtBytes + 8192;

    if (ws_size >= csrNeed) {
        char* ws = (char*)d_ws;
        int* cnt      = (int*)ws;
        int* row_ptr  = (int*)(ws + alignN);
        float* deginv = (float*)(ws + 2 * alignN);
        int* col      = (int*)(ws + 3 * alignN);
        unsigned short* X0  = (unsigned short*)(ws + 3 * alignN + alignE);
        unsigned short* X1  = (unsigned short*)(ws + 3 * alignN + alignE + xBytes);
        unsigned short* WT0 = (unsigned short*)(ws + 3 * alignN + alignE + 2 * xBytes);
        unsigned short* WT1 = WT0 + 64 * 128;
        unsigned short* WT2 = WT1 + 64 * 128;
        int* bsum = (int*)(ws + 3 * alignN + alignE + 2 * xBytes + 3 * wtBytes);

        // CSR build
        hipMemsetAsync(cnt, 0, (size_t)n_nodes * sizeof(int), stream);
        hist_kernel<<<eBlocks, blk, 0, stream>>>(dst, cnt, n_edges);
        scan1_kernel<<<nBlocks1024, blk, 0, stream>>>(cnt, bsum, n_nodes);
        scan2_kernel<<<1, 1024, 0, stream>>>(bsum, nBlocks1024);
        scan3_kernel<<<nBlocks1024, blk, 0, stream>>>(cnt, bsum, row_ptr, deginv, n_nodes, n_edges);
        hipMemsetAsync(cnt, 0, (size_t)n_nodes * sizeof(int), stream);
        fill_kernel<<<eBlocks, blk, 0, stream>>>(src, dst, row_ptr, cnt, col, n_edges);

        // staging
        convert_kernel<<<(n_nodes * 16 + 255) / 256, blk, 0, stream>>>(features, X0, n_nodes);
        wtrans_kernel<<<32, blk, 0, stream>>>(Ws0, Wn0, WT0);
        wtrans_kernel<<<32, blk, 0, stream>>>(Ws1, Wn1, WT1);
        wtrans_kernel<<<32, blk, 0, stream>>>(Ws2, Wn2, WT2);

        // layer 0: X0 -> X1
        aggregate_bf16_kernel<<<waveBlocks, blk, 0, stream>>>(X0, row_ptr, col, deginv, n_nodes);
        linear_mfma_kernel<<<linBlocks, blk, 0, stream>>>(X0, WT0, b0, X1, nullptr, n_nodes, 1);
        // layer 1: X1 -> X0
        aggregate_bf16_kernel<<<waveBlocks, blk, 0, stream>>>(X1, row_ptr, col, deginv, n_nodes);
        linear_mfma_kernel<<<linBlocks, blk, 0, stream>>>(X1, WT1, b1, X0, nullptr, n_nodes, 1);
        // layer 2: X0 -> d_out (f32)
        aggregate_bf16_kernel<<<waveBlocks, blk, 0, stream>>>(X0, row_ptr, col, deginv, n_nodes);
        linear_mfma_kernel<<<linBlocks, blk, 0, stream>>>(X0, WT2, b2, nullptr, out, n_nodes, 0);
    } else {
        // fallback: round-1 atomic-scatter path (f32)
        char* ws = (char*)d_ws;
        size_t degBytes = (((size_t)n_nodes * 4) + 255) / 256 * 256;
        float* deg = (float*)ws;
        float* agg = (float*)(ws + degBytes);
        float* h1  = agg + (size_t)n_nodes * NF;
        int scatBlocks = (n_edges * 16 + 255) / 256;
        size_t rowBytes = (size_t)n_nodes * NF * sizeof(float);

        hipMemsetAsync(deg, 0, (size_t)n_nodes * sizeof(float), stream);
        deg_kernel<<<eBlocks, blk, 0, stream>>>(dst, deg, n_edges);
        inv_kernel<<<(n_nodes + 255) / 256, blk, 0, stream>>>(deg, n_nodes);

        hipMemsetAsync(agg, 0, rowBytes, stream);
        scatter_kernel<<<scatBlocks, blk, 0, stream>>>(features, src, dst, agg, n_edges);
        linear_kernel<<<waveBlocks, blk, 0, stream>>>(features, agg, deg, Ws0, Wn0, b0, out, n_nodes, 1, 1);

        hipMemsetAsync(agg, 0, rowBytes, stream);
        scatter_kernel<<<scatBlocks, blk, 0, stream>>>(out, src, dst, agg, n_edges);
        linear_kernel<<<waveBlocks, blk, 0, stream>>>(out, agg, deg, Ws1, Wn1, b1, h1, n_nodes, 1, 1);

        hipMemsetAsync(agg, 0, rowBytes, stream);
        scatter_kernel<<<scatBlocks, blk, 0, stream>>>(h1, src, dst, agg, n_edges);
        linear_kernel<<<waveBlocks, blk, 0, stream>>>(h1, agg, deg, Ws2, Wn2, b2, out, n_nodes, 0, 1);
    }
}